// Round 7
// baseline (1354.567 us; speedup 1.0000x reference)
//
#include <hip/hip_runtime.h>
#include <stdint.h>

#define T_ 65536
#define HW_ 16384
#define SCALE_F 0.08838834764831845f
#define EPS_ 1e-4f

typedef unsigned short u16;
typedef unsigned int u32;
typedef __attribute__((ext_vector_type(4))) float f32x4;
typedef __attribute__((ext_vector_type(8))) __bf16 bf16x8v;

union frag_u { u16 h[8]; bf16x8v v; uint4 q4; };

__device__ __forceinline__ float bf2f(u16 h) {
    union { u32 u; float f; } x; x.u = ((u32)h) << 16; return x.f;
}
__device__ __forceinline__ u16 f2bf(float f) {
    union { u32 u; float f; } x; x.f = f;
    u32 u = x.u;
    return (u16)((u + 0x7FFFu + ((u >> 16) & 1u)) >> 16);
}
__device__ __forceinline__ f32x4 mfma_b(bf16x8v a, bf16x8v b, f32x4 c) {
    return __builtin_amdgcn_mfma_f32_16x16x32_bf16(a, b, c, 0, 0, 0);
}

// window-token -> global token
__device__ __forceinline__ int tmap(int br, int tbase, int blk, int tok) {
    return (br == 0) ? (tbase + (tok >> 2) * 128 + blk * 4 + (tok & 3))
                     : (tbase + blk * 512 + tok);
}

__global__ void sentinel_kernel(float* out, float code) {
    if (blockIdx.x == 0 && threadIdx.x == 0) out[0] = code;
}

// ---------------- K1: LayerNorm over C, x fp32 [B,C,H,W] -> xn bf16 [t][c] ----------------
__global__ __launch_bounds__(256) void ln_kernel(const float* __restrict__ x,
        const float* __restrict__ g, const float* __restrict__ bta, u16* __restrict__ xn) {
    int t = blockIdx.x * 256 + threadIdx.x;
    int b = t >> 14, hw = t & 16383;
    const float* xb = x + (size_t)b * 256 * HW_ + hw;
    float s = 0.f, ss = 0.f;
    for (int c = 0; c < 256; ++c) {
        float v = xb[(size_t)c * HW_];
        s += v; ss += v * v;
    }
    float mu = s * (1.f / 256.f);
    float var = ss * (1.f / 256.f) - mu * mu;
    float rstd = rsqrtf(var + EPS_);
    u16* o = xn + (size_t)t * 256;
    for (int c0 = 0; c0 < 256; c0 += 8) {
        u16 tmp[8] __attribute__((aligned(16)));
        #pragma unroll
        for (int j = 0; j < 8; ++j) {
            int c = c0 + j;
            float v = xb[(size_t)c * HW_];
            tmp[j] = f2bf((v - mu) * rstd * g[c] + bta[c]);
        }
        *(uint4*)(o + c0) = *(const uint4*)tmp;
    }
}

// ---------------- K2: per-branch K/V GEMM -> kv planes [256][65536] bf16 ----------------
// plane p<128: K local-ch p (w col 256+br*128+p); p>=128: V local-ch p-128 (w col 384+br*128+p)
__global__ __launch_bounds__(256) void kv_gemm(const float* __restrict__ w,
        const u16* __restrict__ xn, u16* __restrict__ kv, int br) {
    __shared__ __align__(16) u16 a_tile[128 * 32];
    __shared__ __align__(16) u16 b_tile[128 * 32];
    int m0 = blockIdx.y * 128, n0 = blockIdx.x * 128;
    int tid = threadIdx.x;
    int lane = tid & 63, wid = tid >> 6;
    int wm = wid >> 1, wn = wid & 1;
    int l15 = lane & 15, quad = lane >> 4;
    f32x4 acc[4][4] = {};
    for (int k0 = 0; k0 < 256; k0 += 32) {
        __syncthreads();
        for (int idx = tid; idx < 4096; idx += 256) {
            int row = idx & 127, kk = idx >> 7;
            int m = m0 + row;
            int col = (m < 128) ? (256 + br * 128 + m) : (384 + br * 128 + m);
            a_tile[row * 32 + kk] = f2bf(w[(size_t)(k0 + kk) * 768 + col]);
        }
        for (int ch = tid; ch < 512; ch += 256) {
            int row = ch >> 2, cc = (ch & 3) * 8;
            *(uint4*)&b_tile[row * 32 + cc] = *(const uint4*)&xn[(size_t)(n0 + row) * 256 + k0 + cc];
        }
        __syncthreads();
        bf16x8v af[4], bf[4];
        #pragma unroll
        for (int i = 0; i < 4; ++i) {
            af[i] = *(const bf16x8v*)&a_tile[(wm * 64 + i * 16 + l15) * 32 + quad * 8];
            bf[i] = *(const bf16x8v*)&b_tile[(wn * 64 + i * 16 + l15) * 32 + quad * 8];
        }
        #pragma unroll
        for (int i = 0; i < 4; ++i)
            #pragma unroll
            for (int j = 0; j < 4; ++j)
                acc[i][j] = mfma_b(af[i], bf[j], acc[i][j]);
    }
    #pragma unroll
    for (int i = 0; i < 4; ++i) {
        int mbase = m0 + wm * 64 + i * 16 + quad * 4;
        #pragma unroll
        for (int j = 0; j < 4; ++j) {
            int nc = n0 + wn * 64 + j * 16 + l15;
            #pragma unroll
            for (int r = 0; r < 4; ++r)
                kv[(size_t)(mbase + r) * T_ + nc] = f2bf(acc[i][j][r]);
        }
    }
}

// ---------------- K3: attention, block = (window wi, quarter qq); Q fused ----------------
// xcb: per-branch xc half, write xcb[t*stride + cl], cl = 2*cd + h
__global__ __launch_bounds__(256) void attn_kernel(const float* __restrict__ w,
        const u16* __restrict__ xn, const u16* __restrict__ kv,
        u16* __restrict__ xcb, int br, int stride) {
    __shared__ __align__(16) u16 w_lds[64 * 40];    //  5120 B  [cd][kk]
    __shared__ __align__(16) u16 q_lds[128 * 72];   // 18432 B  [q][cd]
    __shared__ __align__(16) u16 k_lds[128 * 72];   // 18432 B  [tok][cd]
    __shared__ __align__(16) u16 p_lds[64 * 136];   // 17408 B  [qrow][j]
    int wi = blockIdx.x >> 2, qq = blockIdx.x & 3;
    int b = wi >> 5, blk = wi & 31;
    int tbase = b * HW_;
    int tid = threadIdx.x, lane = tid & 63, wid = tid >> 6;
    int l15 = lane & 15, quad = lane >> 4;
    // A-frag token addresses for Q-GEMM (wave's 2 q-tiles)
    int taddr[2];
    #pragma unroll
    for (int qi2 = 0; qi2 < 2; ++qi2)
        taddr[qi2] = tmap(br, tbase, blk, qq * 128 + wid * 32 + qi2 * 16 + l15);

    for (int h = 0; h < 2; ++h) {
        // ---- Q-phase: Q_h[128 q][64 cd] = xn_rows @ w[:, br*128 + 2cd + h]
        f32x4 accq[2][4] = {};
        for (int kc = 0; kc < 8; ++kc) {
            __syncthreads();
            for (int idx = tid; idx < 2048; idx += 256) {
                int cd = idx & 63, kk = idx >> 6;
                w_lds[cd * 40 + kk] = f2bf(w[(size_t)(kc * 32 + kk) * 768 + br * 128 + 2 * cd + h]);
            }
            __syncthreads();
            uint4 aq[2];
            #pragma unroll
            for (int qi2 = 0; qi2 < 2; ++qi2)
                aq[qi2] = *(const uint4*)&xn[(size_t)taddr[qi2] * 256 + kc * 32 + quad * 8];
            #pragma unroll
            for (int nt = 0; nt < 4; ++nt) {
                bf16x8v bw = *(const bf16x8v*)&w_lds[(nt * 16 + l15) * 40 + quad * 8];
                #pragma unroll
                for (int qi2 = 0; qi2 < 2; ++qi2) {
                    frag_u a; a.q4 = aq[qi2];
                    accq[qi2][nt] = mfma_b(a.v, bw, accq[qi2][nt]);
                }
            }
        }
        __syncthreads();
        #pragma unroll
        for (int qi2 = 0; qi2 < 2; ++qi2)
            #pragma unroll
            for (int nt = 0; nt < 4; ++nt)
                #pragma unroll
                for (int r = 0; r < 4; ++r) {
                    int q = wid * 32 + qi2 * 16 + quad * 4 + r;
                    int cd = nt * 16 + l15;
                    q_lds[q * 72 + cd] = f2bf(accq[qi2][nt][r]);
                }
        __syncthreads();

        for (int qp = 0; qp < 2; ++qp) {
            int qr = qp * 64 + wid * 16 + l15;   // A-frag q-row
            frag_u af[2];
            #pragma unroll
            for (int kc2 = 0; kc2 < 2; ++kc2)
                af[kc2].v = *(const bf16x8v*)&q_lds[qr * 72 + kc2 * 32 + quad * 8];
            // ---- S = Q·K^T over 4 key chunks of 128
            f32x4 acc_s[32];
            for (int ch = 0; ch < 4; ++ch) {
                __syncthreads();
                for (int idx = tid; idx < 8192; idx += 256) {
                    int tok = idx & 127, cd = idx >> 7;
                    k_lds[tok * 72 + cd] = kv[(size_t)(2 * cd + h) * T_ + tmap(br, tbase, blk, ch * 128 + tok)];
                }
                __syncthreads();
                #pragma unroll
                for (int js = 0; js < 8; ++js) {
                    f32x4 z = {0.f, 0.f, 0.f, 0.f};
                    bf16x8v b0 = *(const bf16x8v*)&k_lds[(js * 16 + l15) * 72 + quad * 8];
                    bf16x8v b1 = *(const bf16x8v*)&k_lds[(js * 16 + l15) * 72 + 32 + quad * 8];
                    z = mfma_b(af[0].v, b0, z);
                    z = mfma_b(af[1].v, b1, z);
                    acc_s[ch * 8 + js] = z;
                }
            }
            // ---- softmax (rows = quad*4+r within wave's 16 q)
            float mx[4] = {-1e30f, -1e30f, -1e30f, -1e30f};
            #pragma unroll
            for (int js = 0; js < 32; ++js)
                #pragma unroll
                for (int r = 0; r < 4; ++r) mx[r] = fmaxf(mx[r], acc_s[js][r]);
            #pragma unroll
            for (int d = 1; d < 16; d <<= 1)
                #pragma unroll
                for (int r = 0; r < 4; ++r) mx[r] = fmaxf(mx[r], __shfl_xor(mx[r], d, 16));
            float lsum[4] = {0.f, 0.f, 0.f, 0.f};
            #pragma unroll
            for (int js = 0; js < 32; ++js)
                #pragma unroll
                for (int r = 0; r < 4; ++r) {
                    float p = __expf((acc_s[js][r] - mx[r]) * SCALE_F);
                    acc_s[js][r] = p;
                    lsum[r] += p;
                }
            #pragma unroll
            for (int d = 1; d < 16; d <<= 1)
                #pragma unroll
                for (int r = 0; r < 4; ++r) lsum[r] += __shfl_xor(lsum[r], d, 16);
            float linv[4];
            #pragma unroll
            for (int r = 0; r < 4; ++r) linv[r] = 1.f / lsum[r];
            // ---- O = P·V via p_lds chunks; V gathered from global planes
            f32x4 acc_o[4] = {};
            for (int ch = 0; ch < 4; ++ch) {
                __syncthreads();
                #pragma unroll
                for (int js = 0; js < 8; ++js)
                    #pragma unroll
                    for (int r = 0; r < 4; ++r)
                        p_lds[(wid * 16 + quad * 4 + r) * 136 + js * 16 + l15] = f2bf(acc_s[ch * 8 + js][r]);
                __syncthreads();
                #pragma unroll
                for (int jc = 0; jc < 4; ++jc) {
                    bf16x8v pf = *(const bf16x8v*)&p_lds[(wid * 16 + l15) * 136 + jc * 32 + quad * 8];
                    int j0 = ch * 128 + jc * 32 + quad * 8;
                    #pragma unroll
                    for (int cs = 0; cs < 4; ++cs) {
                        int cd = cs * 16 + l15;
                        const u16* vp = kv + (size_t)(128 + 2 * cd + h) * T_;
                        frag_u vf;
                        if (br == 1) {
                            vf.q4 = *(const uint4*)&vp[tbase + blk * 512 + j0];
                        } else {
                            int t0 = tbase + (j0 >> 2) * 128 + blk * 4;
                            *(uint2*)&vf.h[0] = *(const uint2*)&vp[t0];
                            *(uint2*)&vf.h[4] = *(const uint2*)&vp[t0 + 128];
                        }
                        acc_o[cs] = mfma_b(pf, vf.v, acc_o[cs]);
                    }
                }
            }
            // ---- epilogue: xcb[t][cl], cl = 2*cd + h
            #pragma unroll
            for (int cs = 0; cs < 4; ++cs) {
                int cl = 2 * (cs * 16 + l15) + h;
                #pragma unroll
                for (int r = 0; r < 4; ++r) {
                    int q = qq * 128 + qp * 64 + wid * 16 + quad * 4 + r;
                    int t2 = tmap(br, tbase, blk, q);
                    xcb[(size_t)t2 * stride + cl] = f2bf(acc_o[cs][r] * linv[r]);
                }
            }
        }
    }
}

// ---------------- K3b: LePE depthwise 3x3 (window-local), xcb += conv(v)+bias ----------------
__global__ __launch_bounds__(256) void lepe_kernel(const u16* __restrict__ vplanes,
        const float* __restrict__ lw, const float* __restrict__ lb,
        u16* __restrict__ xcb, int br, int stride) {
    int idx = blockIdx.x * 256 + threadIdx.x;   // idx = cl*65536 + t
    int cl = idx >> 16, t = idx & 65535;
    int hw = t & 16383;
    int y = hw >> 7, xw = hw & 127;
    const u16* vp = vplanes + (size_t)cl * T_;
    const float* wp = lw + cl * 9;
    float acc = lb[cl];
    int iy = (br == 0) ? y : (y & 3);
    int ix = (br == 0) ? (xw & 3) : xw;
    int ylim = (br == 0) ? 128 : 4;
    int xlim = (br == 0) ? 4 : 128;
    #pragma unroll
    for (int ky = 0; ky < 3; ++ky) {
        int yy = iy + ky - 1;
        if (yy < 0 || yy >= ylim) continue;
        #pragma unroll
        for (int kx = 0; kx < 3; ++kx) {
            int xx = ix + kx - 1;
            if (xx < 0 || xx >= xlim) continue;
            acc += wp[ky * 3 + kx] * bf2f(vp[t + (ky - 1) * 128 + (kx - 1)]);
        }
    }
    u16* p = &xcb[(size_t)t * stride + cl];
    *p = f2bf(bf2f(*p) + acc);
}

// ---------------- K4: proj GEMM -> out fp32 [B][C][H][W] ----------------
// xc0: [t][128] bf16 (k<128); xc1 via xn overlay: xn[t*256 + k] for k in [128,256)
__global__ __launch_bounds__(256) void proj_kernel(const float* __restrict__ pw,
        const u16* __restrict__ xc0, const u16* __restrict__ xnov,
        const float* __restrict__ pb, float* __restrict__ out) {
    __shared__ __align__(16) u16 a_tile[128 * 32];
    __shared__ __align__(16) u16 b_tile[128 * 32];
    int m0 = blockIdx.y * 128, n0 = blockIdx.x * 128;
    int tid = threadIdx.x;
    int lane = tid & 63, wid = tid >> 6;
    int wm = wid >> 1, wn = wid & 1;
    int l15 = lane & 15, quad = lane >> 4;
    f32x4 acc[4][4] = {};
    for (int k0 = 0; k0 < 256; k0 += 32) {
        __syncthreads();
        for (int idx = tid; idx < 4096; idx += 256) {
            int kk = idx & 31, row = idx >> 5;
            a_tile[row * 32 + kk] = f2bf(pw[(size_t)(m0 + row) * 256 + k0 + kk]);
        }
        for (int ch = tid; ch < 512; ch += 256) {
            int row = ch >> 2, cc = (ch & 3) * 8;
            uint4 v;
            if (k0 < 128) v = *(const uint4*)&xc0[(size_t)(n0 + row) * 128 + k0 + cc];
            else          v = *(const uint4*)&xnov[(size_t)(n0 + row) * 256 + k0 + cc];
            *(uint4*)&b_tile[row * 32 + cc] = v;
        }
        __syncthreads();
        bf16x8v af[4], bf[4];
        #pragma unroll
        for (int i = 0; i < 4; ++i) {
            af[i] = *(const bf16x8v*)&a_tile[(wm * 64 + i * 16 + l15) * 32 + quad * 8];
            bf[i] = *(const bf16x8v*)&b_tile[(wn * 64 + i * 16 + l15) * 32 + quad * 8];
        }
        #pragma unroll
        for (int i = 0; i < 4; ++i)
            #pragma unroll
            for (int j = 0; j < 4; ++j)
                acc[i][j] = mfma_b(af[i], bf[j], acc[i][j]);
    }
    #pragma unroll
    for (int i = 0; i < 4; ++i) {
        int mbase = m0 + wm * 64 + i * 16 + quad * 4;
        #pragma unroll
        for (int j = 0; j < 4; ++j) {
            int nc = n0 + wn * 64 + j * 16 + l15;
            #pragma unroll
            for (int r = 0; r < 4; ++r) {
                int m = mbase + r;
                out[((size_t)(nc >> 14) * 256 + m) * HW_ + (nc & 16383)] = acc[i][j][r] + pb[m];
            }
        }
    }
}

extern "C" void kernel_launch(void* const* d_in, const int* in_sizes, int n_in,
                              void* d_out, int out_size, void* d_ws, size_t ws_size,
                              hipStream_t stream) {
    const float* x     = (const float*)d_in[0];
    const float* ln_g  = (const float*)d_in[1];
    const float* ln_b  = (const float*)d_in[2];
    const float* w_qkv = (const float*)d_in[3];
    const float* lw1   = (const float*)d_in[4];
    const float* lb1   = (const float*)d_in[5];
    const float* lw2   = (const float*)d_in[6];
    const float* lb2   = (const float*)d_in[7];
    const float* pw    = (const float*)d_in[8];
    const float* pb    = (const float*)d_in[9];
    float* out = (float*)d_out;          // fp32 output (reference computes in float32)
    u16* out_u16 = (u16*)d_out;          // 16 MiB scratch: xc0 half during pipeline
    char* ws = (char*)d_ws;

    if (ws_size < 67108864) {
        sentinel_kernel<<<dim3(1), dim3(64), 0, stream>>>(out, 1.0e6f + (float)(ws_size >> 20));
        return;
    }

    u16* xn  = (u16*)ws;                 // [65536][256] bf16 = 32 MiB; rows' 2nd halves become xc1
    u16* kvb = (u16*)(ws + 33554432);    // per-branch K[128]+V[128] planes = 32 MiB

    ln_kernel<<<dim3(256), dim3(256), 0, stream>>>(x, ln_g, ln_b, xn);
    // branch 0: xc0 -> d_out (u16, stride 128)
    kv_gemm<<<dim3(512, 2), dim3(256), 0, stream>>>(w_qkv, xn, kvb, 0);
    attn_kernel<<<dim3(512), dim3(256), 0, stream>>>(w_qkv, xn, kvb, out_u16, 0, 128);
    lepe_kernel<<<dim3(32768), dim3(256), 0, stream>>>(kvb + (size_t)128 * T_, lw1, lb1, out_u16, 0, 128);
    // branch 1: xc1 -> xn overlay (stride 256, offset 128)
    kv_gemm<<<dim3(512, 2), dim3(256), 0, stream>>>(w_qkv, xn, kvb, 1);
    attn_kernel<<<dim3(512), dim3(256), 0, stream>>>(w_qkv, xn, kvb, xn + 128, 1, 256);
    lepe_kernel<<<dim3(32768), dim3(256), 0, stream>>>(kvb + (size_t)128 * T_, lw2, lb2, xn + 128, 1, 256);
    // free d_out: move xc0 into ws B (K planes dead)
    hipMemcpyAsync(kvb, out_u16, 16777216, hipMemcpyDeviceToDevice, stream);
    proj_kernel<<<dim3(512, 2), dim3(256), 0, stream>>>(pw, kvb, xn, pb, out);
}